// Round 16
// baseline (327.696 us; speedup 1.0000x reference)
//
#include <hip/hip_runtime.h>

#define ECE_BINS 15
#define NTHREADS 256
#define NBLOCKS  2048            // 8 blocks/CU x 256 CUs -> 100% occupancy (8KB LDS, low VGPR)
#define NSUB     64              // sub = lane id -> all lanes distinct LDS addresses
#define CNT_SHIFT 42
#define COR_SHIFT 52
#define CONF_MASK ((1ull << CNT_SHIFT) - 1)
// packed cell: [0:41] Q32 conf sum, [42:51] count, [52:63] correct
// per-cell bounds: <=4 threads x <=40 elems = 160 -> count<2^10, conf<160*2^32<2^40: no carries

__global__ __launch_bounds__(256) void ece_fused_kernel(
    const int* __restrict__ preds,
    const int* __restrict__ targets,
    const float* __restrict__ confs,
    int n,
    unsigned long long* __restrict__ ws,   // [0..14] cnt|corr<<32, [15..29] Q32 sums, [30] ticket
    float* __restrict__ out)
{
    __shared__ unsigned long long hist[ECE_BINS + 1][NSUB];   // row 15 = dummy sink for idx<0
    for (int i = threadIdx.x; i < (ECE_BINS + 1) * NSUB; i += NTHREADS)
        (&hist[0][0])[i] = 0ull;
    __syncthreads();

    const int  sub = threadIdx.x & (NSUB - 1);
    const long tid = (long)blockIdx.x * NTHREADS + threadIdx.x;
    const long S   = (long)gridDim.x * NTHREADS;
    const int nvec = n >> 2;
    const int4*   p4 = (const int4*)preds;
    const int4*   t4 = (const int4*)targets;
    const float4* c4 = (const float4*)confs;

    for (long i = tid; i < nvec; i += S) {
        int4 p = p4[i]; int4 t = t4[i]; float4 c = c4[i];
        const int   pv[4] = {p.x, p.y, p.z, p.w};
        const int   tv[4] = {t.x, t.y, t.z, t.w};
        const float cv[4] = {c.x, c.y, c.z, c.w};
        #pragma unroll
        for (int j = 0; j < 4; ++j) {
            // reference math: ceil(c*15) in fp32; i0 in [0,15]; i0<=0 -> no bin (dummy row)
            int i0  = (int)ceilf(cv[j] * 15.0f);
            int row = (i0 <= 0) ? ECE_BINS : (i0 - 1);
            // exact Q32: c*2^32 is exactly representable in fp32; cvt_u32 truncates = floor
            unsigned q = (unsigned)(cv[j] * 4294967296.0f);
            unsigned long long val = (unsigned long long)q | (1ull << CNT_SHIFT)
                                   | ((pv[j] == tv[j]) ? (1ull << COR_SHIFT) : 0ull);
            atomicAdd(&hist[row][sub], val);
        }
    }
    // scalar tail (n % 4 != 0; empty for n = 20M)
    for (long k = ((long)nvec << 2) + tid; k < n; k += S) {
        float cf = confs[k];
        int i0  = (int)ceilf(cf * 15.0f);
        int row = (i0 <= 0) ? ECE_BINS : (i0 - 1);
        unsigned q = (unsigned)(cf * 4294967296.0f);
        unsigned long long val = (unsigned long long)q | (1ull << CNT_SHIFT)
                               | ((preds[k] == targets[k]) ? (1ull << COR_SHIFT) : 0ull);
        atomicAdd(&hist[row][sub], val);
    }

    __syncthreads();
    // unpack + reduce 64 cells per bin; 2 global atomics per bin per block
    if (threadIdx.x < ECE_BINS) {
        const int b = threadIdx.x;
        unsigned long long csum = 0ull;
        unsigned cnt = 0u, corr = 0u;
        #pragma unroll 8
        for (int s = 0; s < NSUB; ++s) {
            unsigned long long v = hist[b][s];
            csum += v & CONF_MASK;
            cnt  += (unsigned)((v >> CNT_SHIFT) & 0x3FFull);
            corr += (unsigned)(v >> COR_SHIFT);
        }
        atomicAdd(&ws[b],            (unsigned long long)cnt | ((unsigned long long)corr << 32));
        atomicAdd(&ws[ECE_BINS + b], csum);
        __threadfence();
    }
    __syncthreads();

    // last-block ticket: finalize ECE (no separate kernel)
    if (threadIdx.x == 0) {
        unsigned long long t = atomicAdd(&ws[30], 1ull);
        if (t == (unsigned long long)gridDim.x - 1ull) {
            __threadfence();
            unsigned long long ca[ECE_BINS], cq[ECE_BINS];
            #pragma unroll
            for (int b = 0; b < ECE_BINS; ++b)
                ca[b] = __hip_atomic_load(&ws[b], __ATOMIC_RELAXED, __HIP_MEMORY_SCOPE_AGENT);
            #pragma unroll
            for (int b = 0; b < ECE_BINS; ++b)
                cq[b] = __hip_atomic_load(&ws[ECE_BINS + b], __ATOMIC_RELAXED, __HIP_MEMORY_SCOPE_AGENT);
            double ece = 0.0;
            #pragma unroll
            for (int b = 0; b < ECE_BINS; ++b) {
                double c = (double)(unsigned)(ca[b] & 0xffffffffull);
                double a = (double)(unsigned)(ca[b] >> 32);
                double s = (double)cq[b] * (1.0 / 4294967296.0);
                if (c > 0.0) ece += fabs(s / c - a / c) * (c / (double)n);
            }
            out[0] = (float)ece;
        }
    }
}

extern "C" void kernel_launch(void* const* d_in, const int* in_sizes, int n_in,
                              void* d_out, int out_size, void* d_ws, size_t ws_size,
                              hipStream_t stream) {
    const int*   preds   = (const int*)d_in[0];
    const int*   targets = (const int*)d_in[1];
    const float* confs   = (const float*)d_in[2];
    float*       out     = (float*)d_out;
    const int    n       = in_sizes[2];

    unsigned long long* ws = (unsigned long long*)d_ws;
    // ws re-poisoned to 0xAA before every timed launch -> zero the 31 u64 slots
    hipMemsetAsync(ws, 0, 31 * sizeof(unsigned long long), stream);

    ece_fused_kernel<<<NBLOCKS, NTHREADS, 0, stream>>>(preds, targets, confs, n, ws, out);
}